// Round 1
// baseline (304.602 us; speedup 1.0000x reference)
//
#include <hip/hip_runtime.h>

constexpr int D   = 128;
constexpr int NEG = 5;

__device__ __forceinline__ float softplus_stable(float z) {
    // softplus(z) = max(z,0) + log1p(exp(-|z|))   (numerically stable)
    return fmaxf(z, 0.0f) + log1pf(expf(-fabsf(z)));
}

__device__ __forceinline__ float wave_reduce_sum(float v) {
#pragma unroll
    for (int off = 32; off > 0; off >>= 1)
        v += __shfl_xor(v, off, 64);
    return v;
}

__global__ void __launch_bounds__(256)
sgns_loss_kernel(const float* __restrict__ emb,
                 const int*   __restrict__ centers,
                 const int*   __restrict__ contexts,
                 const int*   __restrict__ negs,
                 float* __restrict__ out,
                 int P, float invP) {
    __shared__ float bsum;
    if (threadIdx.x == 0) bsum = 0.0f;
    __syncthreads();

    const int lane = threadIdx.x & 63;          // 64 lanes, each owns 2 of 128 elems
    const int wid  = threadIdx.x >> 6;
    const int wpb  = blockDim.x >> 6;
    const int gw   = blockIdx.x * wpb + wid;    // global wave id
    const int nw   = gridDim.x * wpb;           // total waves

    float local = 0.0f;

    for (int p = gw; p < P; p += nw) {
        const float2 v = ((const float2*)(emb + (size_t)centers[p]  * D))[lane];
        const float2 c = ((const float2*)(emb + (size_t)contexts[p] * D))[lane];
        float dpos = v.x * c.x + v.y * c.y;

        float dneg[NEG];
#pragma unroll
        for (int k = 0; k < NEG; ++k) {
            const float2 n = ((const float2*)(emb + (size_t)negs[p * NEG + k] * D))[lane];
            dneg[k] = v.x * n.x + v.y * n.y;
        }

        // pos_loss = -log_sigmoid(dot)   = softplus(-dot)
        float loss = softplus_stable(-wave_reduce_sum(dpos));
        // neg score = -dot; -log_sigmoid(-dot) = softplus(dot)
#pragma unroll
        for (int k = 0; k < NEG; ++k)
            loss += softplus_stable(wave_reduce_sum(dneg[k]));

        local += loss;
    }

    if (lane == 0) atomicAdd(&bsum, local * invP);
    __syncthreads();
    if (threadIdx.x == 0) atomicAdd(out, bsum);
}

extern "C" void kernel_launch(void* const* d_in, const int* in_sizes, int n_in,
                              void* d_out, int out_size, void* d_ws, size_t ws_size,
                              hipStream_t stream) {
    const float* emb      = (const float*)d_in[0];
    const int*   centers  = (const int*)d_in[1];
    const int*   contexts = (const int*)d_in[2];
    const int*   negs     = (const int*)d_in[3];
    float*       out      = (float*)d_out;

    const int P = in_sizes[1];
    const float invP = 1.0f / (float)P;

    hipMemsetAsync(d_out, 0, sizeof(float) * out_size, stream);

    const int block = 256;                       // 4 waves/block
    const int grid  = 2048;                      // 8192 waves, grid-stride over P
    sgns_loss_kernel<<<grid, block, 0, stream>>>(emb, centers, contexts, negs,
                                                 out, P, invP);
}

// Round 2
// 106.146 us; speedup vs baseline: 2.8696x; 2.8696x over previous
//
#include <hip/hip_runtime.h>

constexpr int D      = 128;
constexpr int NEG    = 5;
constexpr int GSIZE  = 8;                 // lanes per pair
constexpr int CHUNKS = D / (4 * GSIZE);   // 4 float4 chunks per lane

__device__ __forceinline__ float softplus_fast(float z) {
    // softplus(z) = max(z,0) + ln2 * log2(1 + 2^(-|z|*log2e)); hw v_exp/v_log
    float t = __builtin_amdgcn_exp2f(-fabsf(z) * 1.44269504f);
    return fmaxf(z, 0.0f) + 0.69314718f * __builtin_amdgcn_logf(1.0f + t);
}

__global__ void __launch_bounds__(256)
sgns_loss_kernel(const float* __restrict__ emb,
                 const int*   __restrict__ centers,
                 const int*   __restrict__ contexts,
                 const int*   __restrict__ negs,
                 float* __restrict__ out,
                 int P, float invP) {
    __shared__ float bsum;
    if (threadIdx.x == 0) bsum = 0.0f;
    __syncthreads();

    const int sub = threadIdx.x & (GSIZE - 1);
    const int gid = (int)((blockIdx.x * blockDim.x + threadIdx.x) >> 3);
    const int ngr = (int)((gridDim.x * blockDim.x) >> 3);

    float local = 0.0f;

    for (int p = gid; p < P; p += ngr) {
        const float4* vr = (const float4*)(emb + (size_t)centers[p]  * D);
        const float4* cr = (const float4*)(emb + (size_t)contexts[p] * D);
        const float4* nr0 = (const float4*)(emb + (size_t)negs[p * NEG + 0] * D);
        const float4* nr1 = (const float4*)(emb + (size_t)negs[p * NEG + 1] * D);
        const float4* nr2 = (const float4*)(emb + (size_t)negs[p * NEG + 2] * D);
        const float4* nr3 = (const float4*)(emb + (size_t)negs[p * NEG + 3] * D);
        const float4* nr4 = (const float4*)(emb + (size_t)negs[p * NEG + 4] * D);

        float acc0 = 0.f, acc1 = 0.f, acc2 = 0.f,
              acc3 = 0.f, acc4 = 0.f, acc5 = 0.f;

#pragma unroll
        for (int c = 0; c < CHUNKS; ++c) {
            const int idx = sub + GSIZE * c;
            const float4 v  = vr[idx];
            const float4 cc = cr[idx];
            const float4 n0 = nr0[idx];
            const float4 n1 = nr1[idx];
            const float4 n2 = nr2[idx];
            const float4 n3 = nr3[idx];
            const float4 n4 = nr4[idx];
            acc0 += v.x*cc.x + v.y*cc.y + v.z*cc.z + v.w*cc.w;
            acc1 += v.x*n0.x + v.y*n0.y + v.z*n0.z + v.w*n0.w;
            acc2 += v.x*n1.x + v.y*n1.y + v.z*n1.z + v.w*n1.w;
            acc3 += v.x*n2.x + v.y*n2.y + v.z*n2.z + v.w*n2.w;
            acc4 += v.x*n3.x + v.y*n3.y + v.z*n3.z + v.w*n3.w;
            acc5 += v.x*n4.x + v.y*n4.y + v.z*n4.z + v.w*n4.w;
        }

        // 3-stage butterfly within the 8-lane group (xor 1,2,4 stay in-group)
#pragma unroll
        for (int off = 1; off < GSIZE; off <<= 1) {
            acc0 += __shfl_xor(acc0, off, 64);
            acc1 += __shfl_xor(acc1, off, 64);
            acc2 += __shfl_xor(acc2, off, 64);
            acc3 += __shfl_xor(acc3, off, 64);
            acc4 += __shfl_xor(acc4, off, 64);
            acc5 += __shfl_xor(acc5, off, 64);
        }

        // all 8 lanes hold full dots; compute redundantly, lane 0 keeps it
        float loss = softplus_fast(-acc0);   // -log_sigmoid(+dot)
        loss += softplus_fast(acc1);         // -log_sigmoid(-dot) = softplus(dot)
        loss += softplus_fast(acc2);
        loss += softplus_fast(acc3);
        loss += softplus_fast(acc4);
        loss += softplus_fast(acc5);
        if (sub == 0) local += loss;
    }

    if (sub == 0 && local != 0.0f) atomicAdd(&bsum, local * invP);
    __syncthreads();
    if (threadIdx.x == 0) atomicAdd(out, bsum);
}

extern "C" void kernel_launch(void* const* d_in, const int* in_sizes, int n_in,
                              void* d_out, int out_size, void* d_ws, size_t ws_size,
                              hipStream_t stream) {
    const float* emb      = (const float*)d_in[0];
    const int*   centers  = (const int*)d_in[1];
    const int*   contexts = (const int*)d_in[2];
    const int*   negs     = (const int*)d_in[3];
    float*       out      = (float*)d_out;

    const int P = in_sizes[1];
    const float invP = 1.0f / (float)P;

    hipMemsetAsync(d_out, 0, sizeof(float) * out_size, stream);

    const int block = 256;   // 32 pair-groups per block
    const int grid  = 2048;  // 65536 groups, ~3.8 pairs each
    sgns_loss_kernel<<<grid, block, 0, stream>>>(emb, centers, contexts, negs,
                                                 out, P, invP);
}